// Round 4
// baseline (285.563 us; speedup 1.0000x reference)
//
#include <hip/hip_runtime.h>

using bf16x8 = __attribute__((ext_vector_type(8))) short;
using f32x4  = __attribute__((ext_vector_type(4))) float;

#define NB 64
#define CLN 1024
#define QLN 128
#define DDN 512

typedef __attribute__((address_space(1))) const void GAS;
typedef __attribute__((address_space(3))) void LAS;

__device__ __forceinline__ unsigned f2bf(float x){
    union { float f; unsigned u; } v; v.f = x;
    unsigned r = v.u + 0x7FFFu + ((v.u >> 16) & 1u);   // RNE
    return r >> 16;
}
__device__ __forceinline__ float bf2f(unsigned short u){
    union { unsigned u; float f; } v; v.u = ((unsigned)u) << 16; return v.f;
}

// ---------------- K0: qT[b][d][j] = bf16(q[b][j][d]); qbf[b][j][d] ----------------
__global__ __launch_bounds__(256) void k0_qprep(const float* __restrict__ q,
        unsigned short* __restrict__ qT, unsigned short* __restrict__ qbf){
    __shared__ float tile[QLN][65];
    const int b  = blockIdx.x;
    const int d0 = blockIdx.y * 64;
    const int t  = threadIdx.x;
    {
        const int col = t & 63, rg = t >> 6;
        #pragma unroll 4
        for (int p = 0; p < 32; ++p){
            int j = p*4 + rg;
            float v = q[(size_t)(b*QLN + j)*DDN + d0 + col];
            tile[j][col] = v;
            qbf[(size_t)(b*QLN + j)*DDN + d0 + col] = (unsigned short)f2bf(v);
        }
    }
    __syncthreads();
    {
        const int j = t & 127, dg = t >> 7;
        #pragma unroll 4
        for (int p = 0; p < 32; ++p){
            int dd = p*2 + dg;
            qT[(size_t)(b*DDN + d0 + dd)*QLN + j] = (unsigned short)f2bf(tile[j][dd]);
        }
    }
}

// ---------------- K0b: s_q[b][j] = q[b][j][:] . w_q ----------------
__global__ __launch_bounds__(256) void k0b_sq(const float* __restrict__ q,
        const float* __restrict__ w_q, float* __restrict__ sq){
    const int b = blockIdx.x;
    const int t = threadIdx.x;
    const int wave = t >> 6, lane = t & 63;
    float wv[8];
    #pragma unroll
    for (int e=0;e<8;++e) wv[e] = w_q[lane*8+e];
    for (int j = wave; j < QLN; j += 4){
        const float* qr = q + (size_t)(b*QLN + j)*DDN + lane*8;
        float s = 0.f;
        #pragma unroll
        for (int e=0;e<8;++e) s += qr[e]*wv[e];
        #pragma unroll
        for (int m=1;m<64;m<<=1) s += __shfl_xor(s, m, 64);
        if (lane==0) sq[b*QLN + j] = s;
    }
}

// ---------------- K1: fused cprep + GEMM1^T -> softmax -> GEMM2^T -> epilogue ----------------
// Transposed MFMA layout: mfma(bfr, af) -> D[j][i] (GEMM1), mfma(a2, b2) -> D[d][i] (GEMM2)
__global__ __launch_bounds__(256,2) void k1_main(
        const float* __restrict__ c, const unsigned short* __restrict__ qbf,
        const unsigned short* __restrict__ qT, const float* __restrict__ sq_ws,
        const float* __restrict__ w_c, const float* __restrict__ w_cq,
        float* __restrict__ out,
        float* __restrict__ vts, float* __restrict__ Mts, float* __restrict__ Sts){
    __shared__ unsigned short sm_u[16384];   // 32KB: staging dbuf (2x16KB) / P^T alias (128x256B)
    __shared__ float sm_vw[16][512];         // 32KB b_att*c partial slabs
    __shared__ float sm_wc[512], sm_wq[512];
    __shared__ float sm_sq[128], sm_m[128], sm_wrow[128], sm_sc[128];
    __shared__ float sm_scp[256], sm_red[8];

    const int bid  = blockIdx.x;
    const int swzb = (bid & 7)*64 + (bid >> 3);   // XCD-aware: batch's 8 tiles share an XCD
    const int b    = swzb >> 3;
    const int tile = swzb & 7;
    const int i0   = tile * 128;
    const int t    = threadIdx.x;
    const int lane = t & 63;
    const int wm   = t >> 6;
    const int l15  = lane & 15;
    const int l4   = lane >> 4;
    const size_t girow0 = (size_t)(b*CLN + i0);

    if (t < 128) sm_sq[t] = sq_ws[b*QLN + t];
    sm_wc[t]     = w_c[t];   sm_wc[t+256] = w_c[t+256];
    sm_wq[t]     = w_cq[t];  sm_wq[t+256] = w_cq[t+256];

    // staging: thread t -> row t>>1, d-half t&1 (32 floats per kc)
    const int srow = t >> 1, shalf = t & 1;
    const float* crow = c + (girow0 + srow)*DDN + shalf*32;
    float scp = 0.f;

    f32x4 ld[8];
    #pragma unroll
    for (int e=0;e<8;++e) ld[e] = *(const f32x4*)(crow + e*4);   // kc=0
    __syncthreads();   // sm_wq/sm_wc visible

    #define DO_STAGE(KC, BUF) do {                                            \
        const int dbase = (KC)*64 + shalf*32;                                 \
        _Pragma("unroll")                                                     \
        for (int q8=0; q8<4; ++q8){                                           \
            f32x4 v0 = ld[q8*2], v1 = ld[q8*2+1];                             \
            f32x4 wq0 = *(const f32x4*)(sm_wq + dbase + q8*8);                \
            f32x4 wq1 = *(const f32x4*)(sm_wq + dbase + q8*8 + 4);            \
            f32x4 wc0 = *(const f32x4*)(sm_wc + dbase + q8*8);                \
            f32x4 wc1 = *(const f32x4*)(sm_wc + dbase + q8*8 + 4);            \
            scp += v0.x*wc0.x + v0.y*wc0.y + v0.z*wc0.z + v0.w*wc0.w          \
                 + v1.x*wc1.x + v1.y*wc1.y + v1.z*wc1.z + v1.w*wc1.w;         \
            uint4 pk;                                                         \
            pk.x = f2bf(v0.x*wq0.x) | (f2bf(v0.y*wq0.y) << 16);               \
            pk.y = f2bf(v0.z*wq0.z) | (f2bf(v0.w*wq0.w) << 16);               \
            pk.z = f2bf(v1.x*wq1.x) | (f2bf(v1.y*wq1.y) << 16);               \
            pk.w = f2bf(v1.z*wq1.z) | (f2bf(v1.w*wq1.w) << 16);               \
            *(uint4*)((char*)(BUF) + srow*128 +                               \
                      ((shalf*64 + q8*16) ^ ((srow&7)<<4))) = pk;             \
        }                                                                     \
    } while(0)

    DO_STAGE(0, sm_u);
    __syncthreads();   // buf0 staged

    f32x4 acc[2][8];
    #pragma unroll
    for (int mi=0;mi<2;++mi)
        #pragma unroll
        for (int nj=0;nj<8;++nj) acc[mi][nj] = f32x4{0.f,0.f,0.f,0.f};

    // ---- GEMM1: D[j][i] = sum_d qbf[j][d] * (c*w_cq)bf[i][d] ----
    const unsigned short* qbbase = qbf + (size_t)b*QLN*DDN;
    for (int kc=0; kc<8; ++kc){
        unsigned short* bufc = sm_u + (kc&1)*8192;
        unsigned short* bufn = sm_u + ((kc&1)^1)*8192;
        if (kc < 7){
            const float* crn = crow + (kc+1)*64;
            #pragma unroll
            for (int e=0;e<8;++e) ld[e] = *(const f32x4*)(crn + e*4);
        }
        #pragma unroll
        for (int ks=0; ks<2; ++ks){
            bf16x8 af[2], bfr[8];
            #pragma unroll
            for (int mi=0;mi<2;++mi){
                const int row = wm*32 + mi*16 + l15;
                af[mi] = *(const bf16x8*)((char*)bufc + row*128 + ((ks*64 + l4*16) ^ ((row&7)<<4)));
            }
            #pragma unroll
            for (int nj=0;nj<8;++nj)
                bfr[nj] = *(const bf16x8*)(qbbase + (size_t)(nj*16+l15)*DDN + kc*64 + ks*32 + l4*8);
            #pragma unroll
            for (int mi=0;mi<2;++mi)
                #pragma unroll
                for (int nj=0;nj<8;++nj)
                    acc[mi][nj] = __builtin_amdgcn_mfma_f32_16x16x32_bf16(bfr[nj], af[mi], acc[mi][nj], 0,0,0);
        }
        if (kc < 7) DO_STAGE(kc+1, bufn);
        __syncthreads();
    }

    // ---- s_c: combine the two half-row partials ----
    sm_scp[t] = scp;
    __syncthreads();
    if (t < 128) sm_sc[t] = sm_scp[2*t] + sm_scp[2*t+1];
    __syncthreads();

    // ---- row softmax: row i fixed per lane (i = wm*32+mi*16+l15), j = nj*16+l4*4+r ----
    f32x4 sq4[8];
    #pragma unroll
    for (int nj=0;nj<8;++nj) sq4[nj] = *(const f32x4*)(sm_sq + nj*16 + l4*4);

    #pragma unroll
    for (int mi=0;mi<2;++mi){
        const int irow = wm*32 + mi*16 + l15;
        float rmax = -1e30f;
        #pragma unroll
        for (int nj=0;nj<8;++nj){
            #pragma unroll
            for (int r=0;r<4;++r){
                float v = acc[mi][nj][r] + sq4[nj][r];
                acc[mi][nj][r] = v;
                rmax = fmaxf(rmax, v);
            }
        }
        rmax = fmaxf(rmax, __shfl_xor(rmax, 16, 64));
        rmax = fmaxf(rmax, __shfl_xor(rmax, 32, 64));
        if (l4 == 0) sm_m[irow] = sm_sc[irow] + rmax;
        float rsum = 0.f;
        #pragma unroll
        for (int nj=0;nj<8;++nj){
            #pragma unroll
            for (int r=0;r<4;++r){
                float pv = __expf(acc[mi][nj][r] - rmax);
                acc[mi][nj][r] = pv;
                rsum += pv;
            }
        }
        rsum += __shfl_xor(rsum, 16, 64);
        rsum += __shfl_xor(rsum, 32, 64);
        const float inv = 1.f / rsum;
        #pragma unroll
        for (int nj=0;nj<8;++nj){
            uint2 u;
            u.x = f2bf(acc[mi][nj][0]*inv) | (f2bf(acc[mi][nj][1]*inv) << 16);
            u.y = f2bf(acc[mi][nj][2]*inv) | (f2bf(acc[mi][nj][3]*inv) << 16);
            *(uint2*)((char*)sm_u + irow*256 + ((nj*32 + l4*8) ^ ((irow&7)<<4))) = u;
        }
    }
    __syncthreads();   // P^T + sm_m visible

    // ---- tile max/sum for b_att + wrow ----
    float v0 = (t < 128) ? sm_m[t] : -1e30f;
    #pragma unroll
    for (int m=1;m<64;m<<=1) v0 = fmaxf(v0, __shfl_xor(v0, m, 64));
    if (lane==0) sm_red[wm] = v0;
    __syncthreads();
    const float mt = fmaxf(sm_red[0], sm_red[1]);
    float ev = (t < 128) ? __expf(sm_m[t] - mt) : 0.f;
    if (t < 128) sm_wrow[t] = ev;
    float es = ev;
    #pragma unroll
    for (int m=1;m<64;m<<=1) es += __shfl_xor(es, m, 64);
    if (lane==0) sm_red[4+wm] = es;
    __syncthreads();
    const float St = sm_red[4]+sm_red[5]+sm_red[6]+sm_red[7];
    float wrow_reg[2];
    wrow_reg[0] = sm_wrow[wm*32 + l15];
    wrow_reg[1] = sm_wrow[wm*32 + 16 + l15];

    // ---- GEMM2: D[d][i] = sum_j qT[d][j] * P^T[i][j]; epilogue float4 ----
    const unsigned short* qtbase = qT + (size_t)b*DDN*QLN;
    for (int dc=0; dc<4; ++dc){
        f32x4 acc2[8][2];
        #pragma unroll
        for (int dt=0;dt<8;++dt){ acc2[dt][0] = f32x4{0,0,0,0}; acc2[dt][1] = f32x4{0,0,0,0}; }
        #pragma unroll
        for (int jc=0; jc<4; ++jc){
            bf16x8 a2[8], b2[2];
            #pragma unroll
            for (int dt=0;dt<8;++dt)
                a2[dt] = *(const bf16x8*)(qtbase + (size_t)(dc*128 + dt*16 + l15)*QLN + jc*32 + l4*8);
            #pragma unroll
            for (int mi=0;mi<2;++mi){
                const int irow = wm*32 + mi*16 + l15;
                b2[mi] = *(const bf16x8*)((char*)sm_u + irow*256 + ((jc*64 + l4*16) ^ ((irow&7)<<4)));
            }
            #pragma unroll
            for (int dt=0;dt<8;++dt)
                #pragma unroll
                for (int mi=0;mi<2;++mi)
                    acc2[dt][mi] = __builtin_amdgcn_mfma_f32_16x16x32_bf16(a2[dt], b2[mi], acc2[dt][mi], 0,0,0);
        }
        #pragma unroll
        for (int dt=0; dt<8; ++dt){
            const int d0 = dc*128 + dt*16 + l4*4;
            f32x4 vp = f32x4{0,0,0,0};
            #pragma unroll
            for (int mi=0; mi<2; ++mi){
                const int irow = wm*32 + mi*16 + l15;
                const size_t gi = girow0 + irow;
                f32x4 cv = *(const f32x4*)(c + gi*DDN + d0);
                f32x4 v  = acc2[dt][mi];
                float* orow = out + gi*2048;
                __builtin_nontemporal_store(cv, (f32x4*)(orow + d0));           // q0 = c (exact)
                __builtin_nontemporal_store(v,  (f32x4*)(orow + 512 + d0));     // q1 = c2q
                f32x4 cq; cq.x=cv.x*v.x; cq.y=cv.y*v.y; cq.z=cv.z*v.z; cq.w=cv.w*v.w;
                __builtin_nontemporal_store(cq, (f32x4*)(orow + 1024 + d0));    // q2 = c*c2q
                const float w = wrow_reg[mi];
                vp.x += w*cv.x; vp.y += w*cv.y; vp.z += w*cv.z; vp.w += w*cv.w;
            }
            vp.x += __shfl_xor(vp.x, 4, 64); vp.y += __shfl_xor(vp.y, 4, 64);
            vp.z += __shfl_xor(vp.z, 4, 64); vp.w += __shfl_xor(vp.w, 4, 64);
            vp.x += __shfl_xor(vp.x, 8, 64); vp.y += __shfl_xor(vp.y, 8, 64);
            vp.z += __shfl_xor(vp.z, 8, 64); vp.w += __shfl_xor(vp.w, 8, 64);
            if (l15 < 4) *(f32x4*)(&sm_vw[wm*4 + l15][d0]) = vp;
        }
    }
    __syncthreads();
    for (int d=t; d<DDN; d+=256){
        float s = 0.f;
        #pragma unroll
        for (int s16=0;s16<16;++s16) s += sm_vw[s16][d];
        vts[(size_t)(b*8 + tile)*DDN + d] = s;
    }
    if (t == 0){ Mts[b*8 + tile] = mt; Sts[b*8 + tile] = St; }
    #undef DO_STAGE
}

// ---------------- K2: combine 8 tiles -> q2c[b][d] ----------------
__global__ __launch_bounds__(256) void k2_combine(const float* __restrict__ vts,
        const float* __restrict__ Mts, const float* __restrict__ Sts,
        float* __restrict__ q2c){
    const int b = blockIdx.x, t = threadIdx.x;
    float Mt[8]; float M = -1e30f;
    #pragma unroll
    for (int i=0;i<8;++i){ Mt[i] = Mts[b*8+i]; M = fmaxf(M, Mt[i]); }
    float coef[8]; float denom = 0.f;
    #pragma unroll
    for (int i=0;i<8;++i){ coef[i] = __expf(Mt[i]-M); denom += coef[i]*Sts[b*8+i]; }
    const float inv = 1.f/denom;
    for (int d=t; d<DDN; d+=256){
        float s = 0.f;
        #pragma unroll
        for (int i=0;i<8;++i) s += coef[i]*vts[(size_t)(b*8+i)*DDN + d];
        q2c[b*DDN + d] = s*inv;
    }
}

// ---------------- K3: q3 = q0 * q2c (q0 = exact c, already in out) ----------------
__global__ __launch_bounds__(256) void k3_cq2c(float* out, const float* __restrict__ q2c){
    const int total = NB*CLN*(DDN/4);
    for (int idx = blockIdx.x*256 + threadIdx.x; idx < total; idx += gridDim.x*256){
        const int d4 = idx & 127;
        const int gi = idx >> 7;
        const int b  = gi >> 10;
        f32x4 cv = *(const f32x4*)(out + (size_t)gi*2048 + d4*4);
        f32x4 qv = *(const f32x4*)(q2c + b*DDN + d4*4);
        f32x4 o; o.x=cv.x*qv.x; o.y=cv.y*qv.y; o.z=cv.z*qv.z; o.w=cv.w*qv.w;
        __builtin_nontemporal_store(o, (f32x4*)(out + (size_t)gi*2048 + 1536 + d4*4));
    }
}

extern "C" void kernel_launch(void* const* d_in, const int* in_sizes, int n_in,
                              void* d_out, int out_size, void* d_ws, size_t ws_size,
                              hipStream_t stream) {
    const float* c    = (const float*)d_in[0];
    const float* q    = (const float*)d_in[1];
    const float* w_c  = (const float*)d_in[2];
    const float* w_q  = (const float*)d_in[4];
    const float* w_cq = (const float*)d_in[6];
    float* out = (float*)d_out;

    char* ws = (char*)d_ws;
    unsigned short* qT  = (unsigned short*)ws;                     // 8 MiB
    unsigned short* qbf = (unsigned short*)(ws + 8388608);         // 8 MiB
    float* sq  = (float*)(ws + 16777216);                          // 32 KB
    float* Mts = (float*)(ws + 16777216 + 32768);                  // 2 KB
    float* Sts = (float*)(ws + 16777216 + 32768 + 2048);           // 2 KB
    float* vts = (float*)(ws + 16777216 + 32768 + 4096);           // 1 MiB
    float* q2c = (float*)(ws + 16777216 + 32768 + 4096 + 1048576); // 128 KB

    k0_qprep<<<dim3(NB, 8), 256, 0, stream>>>(q, qT, qbf);
    k0b_sq<<<NB, 256, 0, stream>>>(q, w_q, sq);
    k1_main<<<NB*8, 256, 0, stream>>>(c, qbf, qT, sq, w_c, w_cq, out, vts, Mts, Sts);
    k2_combine<<<NB, 256, 0, stream>>>(vts, Mts, Sts, q2c);
    k3_cq2c<<<2048, 256, 0, stream>>>(out, q2c);
}